// Round 3
// baseline (658.881 us; speedup 1.0000x reference)
//
#include <hip/hip_runtime.h>
#include <stdint.h>
#include <stddef.h>

// BinaryLinearLayer: out[8192,4096] = x[8192,4096] @ sign(W[4096,4096])^T + sign(bias)[4096]
// R3 (= R2 with compile fix): fuse x->f16 conversion into the GEMM (A staged as
// fp32 via global_load_lds, converted with v_cvt_pkrtz during fragment load).
// Only sign(W)->f16 runs as a separate tiny kernel. XOR-swizzled global->LDS
// granule mapping kills the ds_read_b128 bank conflicts measured in R1
// (SQ_LDS_BANK_CONFLICT 3.35e7).
// Fix vs R2: __builtin_amdgcn_cvt_pkrtz returns ext_vector_type(2) of __fp16,
// not _Float16 — assemble fragments through a union.

#define MDIM 8192
#define NDIM 4096
#define KDIM 4096

typedef __attribute__((ext_vector_type(8))) _Float16 f16x8;
typedef __attribute__((ext_vector_type(2))) __fp16 pk16x2;   // cvt_pkrtz result type
typedef __attribute__((ext_vector_type(4))) float f32x4;
typedef __attribute__((ext_vector_type(8))) short bf16x8;

union frag_u {
  f16x8 v;
  pk16x2 p[4];
};

__device__ __forceinline__ float fsign(float x) {
  return (x > 0.f) ? 1.f : ((x < 0.f) ? -1.f : 0.f);
}

// sign(x) as f16 bits: +1 -> 0x3C00, -1 -> 0xBC00, 0 -> 0
__device__ __forceinline__ short signh(float x) {
  return (x > 0.f) ? (short)0x3C00 : ((x < 0.f) ? (short)0xBC00 : (short)0);
}

__device__ __forceinline__ short f2bf(float f) {
  union { float f; unsigned u; } a; a.f = f;
  unsigned r = a.u + 0x7FFFu + ((a.u >> 16) & 1u);
  return (short)(r >> 16);
}

__device__ __forceinline__ void gl_lds16(const void* g, void* l) {
  __builtin_amdgcn_global_load_lds(
      (const __attribute__((address_space(1))) unsigned*)g,
      (__attribute__((address_space(3))) unsigned*)l,
      16, 0, 0);
}

// ---------------- sign(W) -> f16 conversion ----------------

__global__ void cvt_w_kernel(const float* __restrict__ w, short* __restrict__ o) {
  int i = blockIdx.x * blockDim.x + threadIdx.x;
  float4 v = ((const float4*)w)[i];
  short4 s;
  s.x = signh(v.x); s.y = signh(v.y); s.z = signh(v.z); s.w = signh(v.w);
  ((short4*)o)[i] = s;
}

// ---------------- main GEMM: A fp32 (converted in-kernel), B f16 signs ----------------
// C[m,n] = sum_k A[m,k]*signW[n,k] + sign(bias[n])

__global__ __launch_bounds__(256) void gemm_fx(
    const float* __restrict__ A,   // [MDIM, KDIM] fp32
    const short* __restrict__ B,   // [NDIM, KDIM] f16 sign bits
    const float* __restrict__ bias,
    float* __restrict__ C) {
  // A tile: 128 rows x 32 fp32 = 16 KB (row = 128 B = 8 granules of 16 B)
  // B tile: 128 rows x 32 f16  =  8 KB (row =  64 B = 4 granules of 16 B)
  __shared__ float As[128 * 32];
  __shared__ short Bs[128 * 32];

  const int t    = threadIdx.x;
  const int lane = t & 63;
  const int wm   = (t >> 6) >> 1;   // wave row 0..1
  const int wn   = (t >> 6) & 1;    // wave col 0..1

  const int bm = blockIdx.y * 128;
  const int bn = blockIdx.x * 128;

  f32x4 acc[4][4] = {};

  // ---- staging descriptors (global side carries the XOR swizzle) ----
  // A: 4 issues of 256 lanes x 16 B. Cell c = q*256+t -> row c>>3, granule c&7.
  const float* gA[4]; void* lA[4];
#pragma unroll
  for (int q = 0; q < 4; ++q) {
    const int c = q * 256 + t;
    const int row = c >> 3, g = c & 7;
    const int gg = g ^ (row & 7);                 // swizzled source granule
    gA[q] = A + (size_t)(bm + row) * KDIM + gg * 4;
    lA[q] = (char*)As + c * 16;
  }
  // B: 2 issues. Cell c -> row c>>2, granule c&3.
  const short* gB[2]; void* lB[2];
#pragma unroll
  for (int q = 0; q < 2; ++q) {
    const int c = q * 256 + t;
    const int row = c >> 2, g = c & 3;
    const int gg = g ^ ((row >> 1) & 3);
    gB[q] = B + (size_t)(bn + row) * KDIM + gg * 8;
    lB[q] = (char*)Bs + c * 16;
  }

  const int fr = lane & 15;     // fragment row within 16
  const int kg = lane >> 4;     // k-group 0..3 (8 elements each)

  for (int k0 = 0; k0 < KDIM; k0 += 32) {
#pragma unroll
    for (int q = 0; q < 4; ++q) gl_lds16(gA[q] + k0, lA[q]);
#pragma unroll
    for (int q = 0; q < 2; ++q) gl_lds16(gB[q] + k0, lB[q]);
    __syncthreads();   // compiler drains vmcnt before s_barrier -> LDS ready

    f16x8 af[4], bfr[4];
#pragma unroll
    for (int i = 0; i < 4; ++i) {
      const int r = wm * 64 + i * 16 + fr;
      const char* rb = (const char*)As + r * 128;
      // fragment = global granules 2kg, 2kg+1 -> stored at g ^ (r&7)
      f32x4 lo = *(const f32x4*)(rb + (((2 * kg)     ^ (r & 7)) << 4));
      f32x4 hi = *(const f32x4*)(rb + (((2 * kg + 1) ^ (r & 7)) << 4));
      frag_u u;
      u.p[0] = __builtin_amdgcn_cvt_pkrtz(lo[0], lo[1]);
      u.p[1] = __builtin_amdgcn_cvt_pkrtz(lo[2], lo[3]);
      u.p[2] = __builtin_amdgcn_cvt_pkrtz(hi[0], hi[1]);
      u.p[3] = __builtin_amdgcn_cvt_pkrtz(hi[2], hi[3]);
      af[i] = u.v;
    }
#pragma unroll
    for (int j = 0; j < 4; ++j) {
      const int r = wn * 64 + j * 16 + fr;
      bfr[j] = *(const f16x8*)((const char*)Bs + r * 64 + ((kg ^ ((r >> 1) & 3)) << 4));
    }
#pragma unroll
    for (int i = 0; i < 4; ++i)
#pragma unroll
      for (int j = 0; j < 4; ++j)
        acc[i][j] = __builtin_amdgcn_mfma_f32_16x16x32_f16(af[i], bfr[j], acc[i][j], 0, 0, 0);
    __syncthreads();   // all LDS reads done before next iteration overwrites
  }

  // epilogue: C/D layout col = lane&15, row = (lane>>4)*4 + r
  const int row0 = bm + wm * 64 + ((lane >> 4) << 2);
  const int col0 = bn + wn * 64 + (lane & 15);
#pragma unroll
  for (int j = 0; j < 4; ++j) {
    const int gc = col0 + j * 16;
    const float bs = fsign(bias[gc]);
#pragma unroll
    for (int i = 0; i < 4; ++i) {
      float* cp = C + (size_t)(row0 + i * 16) * NDIM + gc;
#pragma unroll
      for (int r = 0; r < 4; ++r)
        cp[(size_t)r * NDIM] = acc[i][j][r] + bs;
    }
  }
}

// ---------------- fallback: fully fused (no workspace needed) ----------------

__global__ __launch_bounds__(256) void gemm_fused(
    const float* __restrict__ A,
    const float* __restrict__ W,
    const float* __restrict__ bias,
    float* __restrict__ C) {
  __shared__ short As[128 * 32];
  __shared__ short Bs[128 * 32];

  const int t    = threadIdx.x;
  const int lane = t & 63;
  const int wm   = (t >> 6) >> 1;
  const int wn   = (t >> 6) & 1;
  const int bm = blockIdx.y * 128;
  const int bn = blockIdx.x * 128;

  f32x4 acc[4][4] = {};

  const int srow = t >> 1;
  const int scol = (t & 1) << 4;
  const float* pA = A + (size_t)(bm + srow) * KDIM + scol;
  const float* pW = W + (size_t)(bn + srow) * KDIM + scol;
  short* sA = As + srow * 32 + scol;
  short* sB = Bs + srow * 32 + scol;

  const int fr  = lane & 15;
  const int fkB = (lane >> 4) << 4;

  for (int k0 = 0; k0 < KDIM; k0 += 32) {
    float4 va[4], vb[4];
#pragma unroll
    for (int q = 0; q < 4; ++q) {
      va[q] = *(const float4*)(pA + k0 + q * 4);
      vb[q] = *(const float4*)(pW + k0 + q * 4);
    }
    __syncthreads();
    short va_s[16], vb_s[16];
#pragma unroll
    for (int q = 0; q < 4; ++q) {
      va_s[q * 4 + 0] = f2bf(va[q].x); va_s[q * 4 + 1] = f2bf(va[q].y);
      va_s[q * 4 + 2] = f2bf(va[q].z); va_s[q * 4 + 3] = f2bf(va[q].w);
      vb_s[q * 4 + 0] = f2bf(fsign(vb[q].x)); vb_s[q * 4 + 1] = f2bf(fsign(vb[q].y));
      vb_s[q * 4 + 2] = f2bf(fsign(vb[q].z)); vb_s[q * 4 + 3] = f2bf(fsign(vb[q].w));
    }
    bf16x8 ca, cb;
#pragma unroll
    for (int e = 0; e < 8; ++e) { ca[e] = va_s[e]; cb[e] = vb_s[e]; }
    *(bf16x8*)(sA) = ca;
    *(bf16x8*)(sB) = cb;
#pragma unroll
    for (int e = 0; e < 8; ++e) { ca[e] = va_s[8 + e]; cb[e] = vb_s[8 + e]; }
    *(bf16x8*)(sA + 8) = ca;
    *(bf16x8*)(sB + 8) = cb;
    __syncthreads();

    bf16x8 af[4], bfr[4];
#pragma unroll
    for (int i = 0; i < 4; ++i) {
      af[i]  = *(const bf16x8*)((const char*)As + (wm * 64 + i * 16 + fr) * 64 + fkB);
      bfr[i] = *(const bf16x8*)((const char*)Bs + (wn * 64 + i * 16 + fr) * 64 + fkB);
    }
#pragma unroll
    for (int i = 0; i < 4; ++i)
#pragma unroll
      for (int j = 0; j < 4; ++j)
        acc[i][j] = __builtin_amdgcn_mfma_f32_16x16x32_bf16(af[i], bfr[j], acc[i][j], 0, 0, 0);
  }
  __syncthreads();

  const int row0 = bm + wm * 64 + ((lane >> 4) << 2);
  const int col0 = bn + wn * 64 + (lane & 15);
#pragma unroll
  for (int j = 0; j < 4; ++j) {
    const int gc = col0 + j * 16;
    const float bs = fsign(bias[gc]);
#pragma unroll
    for (int i = 0; i < 4; ++i) {
      float* cp = C + (size_t)(row0 + i * 16) * NDIM + gc;
#pragma unroll
      for (int r = 0; r < 4; ++r)
        cp[(size_t)r * NDIM] = acc[i][j][r] + bs;
    }
  }
}

extern "C" void kernel_launch(void* const* d_in, const int* in_sizes, int n_in,
                              void* d_out, int out_size, void* d_ws, size_t ws_size,
                              hipStream_t stream) {
  const float* x    = (const float*)d_in[0];
  const float* w    = (const float*)d_in[1];
  const float* bias = (const float*)d_in[2];
  float* out = (float*)d_out;

  const size_t wb_bytes = (size_t)NDIM * KDIM * 2;   // 33.6 MB

  dim3 grid(NDIM / 128, MDIM / 128);   // 32 x 64 = 2048 blocks

  if (ws_size >= wb_bytes) {
    short* wb = (short*)d_ws;
    cvt_w_kernel<<<(NDIM * (KDIM / 4)) / 256, 256, 0, stream>>>(w, wb);
    gemm_fx<<<grid, 256, 0, stream>>>(x, wb, bias, out);
  } else {
    gemm_fused<<<grid, 256, 0, stream>>>(x, w, bias, out);
  }
}